// Round 7
// baseline (79.718 us; speedup 1.0000x reference)
//
#include <hip/hip_runtime.h>
#include <math.h>

namespace {

constexpr int K = 256, D = 256, P = 40, C = 32;
constexpr int LN = 2048;     // LUT intervals over s in [-1,1]
constexpr int NOUT = K * K;  // 65536
constexpr int ZB = 128;                   // zero-blocks: 128*256*16B = 512 KB (accS+corr)
constexpr int LB = (LN + 1 + 255) / 256;  // LUT blocks
constexpr int NG = P / 2;                 // 20 p-pair groups
constexpr int NGP = 24;                   // padded to multiple of 8 for XCD decode

typedef __attribute__((ext_vector_type(8))) short bf16x8;
typedef __attribute__((ext_vector_type(4))) float f32x4;

__device__ __forceinline__ float tanh_fast(float x) {
  float e = __expf(2.0f * x);
  return 1.0f - __fdividef(2.0f, e + 1.0f);
}

// round-to-nearest bf16 split: (hi16) | (lo16 << 16); hi+lo ~ v to ~2^-18 rel
__device__ __forceinline__ unsigned bf16pair(float v) {
  unsigned u = __float_as_uint(v);
  unsigned hi = (u + 0x7fffu + ((u >> 16) & 1u)) >> 16;
  float lo = v - __uint_as_float(hi << 16);
  unsigned ul = __float_as_uint(lo);
  unsigned lo16 = (ul + 0x7fffu + ((ul >> 16) & 1u)) >> 16;
  return hi | (lo16 << 16);
}

__device__ __forceinline__ void gload16(const void* g, void* l) {
  __builtin_amdgcn_global_load_lds((const __attribute__((address_space(1))) void*)g,
                                   (__attribute__((address_space(3))) void*)l, 16, 0, 0);
}

// ---- prep (+ merged init): blocks [0,2K): L2-norm+transpose+bf16-split;
//      then ZB zero-blocks (accS/corr); then LUT blocks; then pw+cnt block ----
__global__ __launch_bounds__(256) void kprep(const float* __restrict__ e,
                                             const float* __restrict__ ts,
                                             const float* __restrict__ fc1w,
                                             const float* __restrict__ fc1b,
                                             const float* __restrict__ fc2w,
                                             const float* __restrict__ pho_w,
                                             unsigned* __restrict__ Ep,
                                             unsigned* __restrict__ Tp,
                                             float* __restrict__ accz,
                                             float* __restrict__ tab,
                                             float* __restrict__ pwv,
                                             unsigned* __restrict__ cnt) {
  const int bid = blockIdx.x;
  const int t = threadIdx.x;
  if (bid >= 2 * K) {
    int ib = bid - 2 * K;
    if (ib < ZB) {
      ((float4*)accz)[(size_t)ib * 256 + t] = make_float4(0.f, 0.f, 0.f, 0.f);
      return;
    }
    ib -= ZB;
    if (ib < LB) {
      int i = ib * 256 + t;
      if (i <= LN) {
        float s = -1.0f + (float)i * (2.0f / LN);
        float g = 0.f;
#pragma unroll
        for (int c = 0; c < C; ++c) g = fmaf(tanh_fast(fmaf(s, fc1w[c], fc1b[c])), fc2w[c], g);
        tab[i] = tanh_fast(g * s);
      }
      return;
    }
    // pw block: pwv[0..P) normalized weights, pwv[P] = sum; zero region counters
    float wmin = pho_w[0], wmax = pho_w[0];
    for (int i = 1; i < P; ++i) {
      float v = pho_w[i];
      wmin = fminf(wmin, v);
      wmax = fmaxf(wmax, v);
    }
    float inv = 1.0f / (1e-6f + wmax - wmin);
    if (t < P) pwv[t] = (pho_w[t] - wmin) * inv;
    if (t == 64) {
      float sum = 0.f;
      for (int i = 0; i < P; ++i) sum += (pho_w[i] - wmin) * inv;
      pwv[P] = sum;
    }
    if (t >= 128 && t < 192) cnt[t - 128] = 0u;
    return;
  }
  // ---- prep path ----
  __shared__ float tile[D * 41];  // padded stride 41
  __shared__ float red[240];
  __shared__ float inv[P];
  const float* x = (bid < K) ? e : ts;
  unsigned* xt = (bid < K) ? Ep : Tp;
  const int a = bid & (K - 1);
  const float4* src4 = (const float4*)(x + (size_t)a * D * P);
#pragma unroll
  for (int i4 = t; i4 < (D * P) / 4; i4 += 256) {
    float4 v = src4[i4];
    int d = i4 / 10;
    int p0 = (i4 - d * 10) * 4;
    float* dst = &tile[d * 41 + p0];
    dst[0] = v.x;
    dst[1] = v.y;
    dst[2] = v.z;
    dst[3] = v.w;
  }
  __syncthreads();
  if (t < 240) {  // 6 threads per column
    int p = t / 6, j = t - (t / 6) * 6;
    float ss = 0.f;
    for (int d = j; d < D; d += 6) {
      float v = tile[d * 41 + p];
      ss = fmaf(v, v, ss);
    }
    red[t] = ss;
  }
  __syncthreads();
  if (t < P) {
    float ss = red[t * 6] + red[t * 6 + 1] + red[t * 6 + 2] + red[t * 6 + 3] +
               red[t * 6 + 4] + red[t * 6 + 5];
    inv[t] = 1.0f / fmaxf(sqrtf(ss), 1e-12f);
  }
  __syncthreads();
  for (int i = t; i < (D * P) / 2; i += 256) {
    int p = i >> 7, d = (i & 127) * 2;
    float iv = inv[p];
    unsigned u0 = bf16pair(tile[d * 41 + p] * iv);
    unsigned u1 = bf16pair(tile[(d + 1) * 41 + p] * iv);
    *(uint2*)&xt[((size_t)p * K + a) * 256 + d] = make_uint2(u0, u1);
  }
}

// ---- per-p-pair MFMA GEMM (split-K=512 bf16, 64x32 tile), XCD-grouped grid,
//      fused LUT epilogue + atomics + last-region-block finalize ----
__global__ __launch_bounds__(256) void kgemm(const unsigned* __restrict__ Ep,
                                             const unsigned* __restrict__ Tp,
                                             const float* __restrict__ tab,
                                             const float* __restrict__ pwv,
                                             float* __restrict__ accS,
                                             float* __restrict__ corr,
                                             unsigned* __restrict__ cnt,
                                             float* __restrict__ out) {
  __shared__ uint4 As4[2][512];  // 2 x 8 KiB: 64 rows x 128 B (swizzled content)
  __shared__ uint4 Bs4[2][256];  // 2 x 4 KiB: 32 rows x 128 B
  __shared__ __align__(16) float lt[LN + 4];
  __shared__ unsigned done_s;
  // XCD-grouped decode: blocks of one p-pair group land on one XCD (id%8 assumption)
  const int id = blockIdx.x;
  const int xcd = id & 7, slot = id >> 3;
  const int gidx = slot >> 5, tile = slot & 31;
  const int g = xcd + 8 * gidx;
  if (g >= NG) return;
  const int p0 = 2 * g;
  const int a0 = (tile & 3) * 64, b0 = (tile >> 2) * 32;
  const int t = threadIdx.x, lane = t & 63, w = t >> 6;

  {  // stage LUT (visible after first K-loop barrier)
    const float4* t4 = (const float4*)tab;
    float4* l4 = (float4*)lt;
#pragma unroll
    for (int i = t; i < LN / 4; i += 256) l4[i] = t4[i];
    if (t == 0) lt[LN] = tab[LN];
  }

  // staging geometry: wave w fills A rows [w*16, w*16+16), B rows [w*8, w*8+8)
  const int lr = lane >> 3, sb = lane & 7;
  const int rA0 = w * 16 + lr, rA1 = rA0 + 8, rB = w * 8 + lr;
  const size_t offA0 = (size_t)(a0 + rA0) * 1024 + ((sb * 16) ^ ((rA0 & 7) << 4));
  const size_t offA1 = (size_t)(a0 + rA1) * 1024 + ((sb * 16) ^ ((rA1 & 7) << 4));
  const size_t offB = (size_t)(b0 + rB) * 1024 + ((sb * 16) ^ ((rB & 7) << 4));
  char* dA0 = (char*)&As4[0][0] + w * 2048;
  char* dA1 = (char*)&As4[1][0] + w * 2048;
  char* dB0 = (char*)&Bs4[0][0] + w * 1024;
  char* dB1 = (char*)&Bs4[1][0] + w * 1024;

  // fragment read geometry
  const int qr = (w >> 1) * 32, qc = (w & 1) * 16;
  const int l15 = lane & 15, hi16 = (lane >> 4) * 16;
  const int rsw = (l15 & 7) << 4;
  const int rowA0 = (qr + l15) * 128, rowA1 = (qr + 16 + l15) * 128;
  const int rowB0 = (qc + l15) * 128;

  const char* Ec = (const char*)Ep;
  const char* Tc = (const char*)Tp;

  // prologue: p0 buffer 0
  gload16(Ec + (size_t)p0 * (K * 1024) + offA0, dA0);
  gload16(Ec + (size_t)p0 * (K * 1024) + offA1, dA0 + 1024);
  gload16(Tc + (size_t)p0 * (K * 1024) + offB, dB0);

  float sc[8] = {0.f, 0.f, 0.f, 0.f, 0.f, 0.f, 0.f, 0.f};
  float cz[8] = {0.f, 0.f, 0.f, 0.f, 0.f, 0.f, 0.f, 0.f};
  const float pwp[2] = {pwv[p0], pwv[p0 + 1]};

#pragma unroll
  for (int pg = 0; pg < 2; ++pg) {
    const char* ce = Ec + (size_t)(p0 + pg) * (K * 1024);
    const char* ct = Tc + (size_t)(p0 + pg) * (K * 1024);
    f32x4 acc0 = {0.f, 0.f, 0.f, 0.f}, acc1 = {0.f, 0.f, 0.f, 0.f};
    for (int ks = 0; ks < 8; ++ks) {
      const int cur = ks & 1;
      __syncthreads();  // drains in-flight gloads; buf[cur] ready
      if (ks < 7) {     // prefetch next K-step of this p
        char* dan = cur ? dA0 : dA1;
        char* dbn = cur ? dB0 : dB1;
        gload16(ce + offA0 + (size_t)(ks + 1) * 128, dan);
        gload16(ce + offA1 + (size_t)(ks + 1) * 128, dan + 1024);
        gload16(ct + offB + (size_t)(ks + 1) * 128, dbn);
      } else if (pg == 0) {  // prologue for p1 flies under p0's epilogue
        const char* ne = Ec + (size_t)(p0 + 1) * (K * 1024);
        const char* nt = Tc + (size_t)(p0 + 1) * (K * 1024);
        gload16(ne + offA0, dA0);
        gload16(ne + offA1, dA0 + 1024);
        gload16(nt + offB, dB0);
      }
      const char* Ac = (const char*)As4[cur];
      const char* Bc = (const char*)Bs4[cur];
#pragma unroll
      for (int kk = 0; kk < 2; ++kk) {
        const int off = (kk * 64 + hi16) ^ rsw;
        bf16x8 af0 = *(const bf16x8*)(Ac + rowA0 + off);
        bf16x8 af1 = *(const bf16x8*)(Ac + rowA1 + off);
        bf16x8 bf0 = *(const bf16x8*)(Bc + rowB0 + off);
        acc0 = __builtin_amdgcn_mfma_f32_16x16x32_bf16(af0, bf0, acc0, 0, 0, 0);
        acc1 = __builtin_amdgcn_mfma_f32_16x16x32_bf16(af1, bf0, acc1, 0, 0, 0);
      }
    }
    // LUT epilogue for this p into register partial sums
#pragma unroll
    for (int j = 0; j < 4; ++j) {
      float s0 = acc0[j], s1 = acc1[j];
      float u0 = fminf(fmaxf((s0 + 1.0f) * (LN / 2), 0.0f), (float)LN);
      float u1 = fminf(fmaxf((s1 + 1.0f) * (LN / 2), 0.0f), (float)LN);
      int i0 = min((int)u0, LN - 1), i1 = min((int)u1, LN - 1);
      float f0 = u0 - (float)i0, f1 = u1 - (float)i1;
      float F0 = fmaf(f0, lt[i0 + 1] - lt[i0], lt[i0]);
      float F1 = fmaf(f1, lt[i1 + 1] - lt[i1], lt[i1]);
      sc[j] = fmaf(F0, pwp[pg], sc[j]);
      sc[j + 4] = fmaf(F1, pwp[pg], sc[j + 4]);
      if (s0 == 0.0f) cz[j] += pwp[pg];
      if (s1 == 0.0f) cz[j + 4] += pwp[pg];
    }
  }

  // accumulate into global planes
  const int ar = a0 + qr + (lane >> 4) * 4;
  const int bc = b0 + qc + l15;
#pragma unroll
  for (int j = 0; j < 4; ++j) {
    atomicAdd(&accS[(ar + j) * K + bc], sc[j]);
    atomicAdd(&accS[(ar + 16 + j) * K + bc], sc[j + 4]);
    if (cz[j] != 0.f) atomicAdd(&corr[(ar + j) * K + bc], cz[j]);
    if (cz[j + 4] != 0.f) atomicAdd(&corr[(ar + 16 + j) * K + bc], cz[j + 4]);
  }

  // last block of this 64x32 region finalizes it
  __threadfence();
  __syncthreads();
  if (t == 0) done_s = (atomicAdd(&cnt[tile], 1u) == NG - 1) ? 1u : 0u;
  __syncthreads();
  if (done_s) {
    const float pwsum = pwv[P];
    const int r = t >> 2, c0 = (t & 3) * 8;
    float o[8];
#pragma unroll
    for (int q = 0; q < 8; ++q) {
      int eidx = (a0 + r) * K + b0 + c0 + q;
      float sS = __hip_atomic_load(&accS[eidx], __ATOMIC_RELAXED, __HIP_MEMORY_SCOPE_AGENT);
      float cC = __hip_atomic_load(&corr[eidx], __ATOMIC_RELAXED, __HIP_MEMORY_SCOPE_AGENT);
      o[q] = sS / (pwsum - cC + 1e-6f);
    }
    float4* dst = (float4*)&out[(a0 + r) * K + b0 + c0];
    dst[0] = make_float4(o[0], o[1], o[2], o[3]);
    dst[1] = make_float4(o[4], o[5], o[6], o[7]);
  }
}

// ---- emergency fallback (no workspace needed) ----
__global__ __launch_bounds__(256) void kmono(const float* __restrict__ enroll,
                                             const float* __restrict__ test,
                                             const float* __restrict__ pho_w,
                                             const float* __restrict__ fc1w,
                                             const float* __restrict__ fc1b,
                                             const float* __restrict__ fc2w,
                                             float* __restrict__ out) {
  __shared__ float w1[C], b1[C], w2[C], pwm[P];
  const int t = threadIdx.x;
  if (t < C) {
    w1[t] = fc1w[t];
    b1[t] = fc1b[t];
    w2[t] = fc2w[t];
  }
  if (t < P) {
    float wmin = pho_w[0], wmax = pho_w[0];
    for (int i = 1; i < P; ++i) {
      float v = pho_w[i];
      wmin = fminf(wmin, v);
      wmax = fmaxf(wmax, v);
    }
    pwm[t] = (pho_w[t] - wmin) / (1e-6f + wmax - wmin);
  }
  __syncthreads();
  const int idx = blockIdx.x * 256 + t;
  const int a = idx >> 8, b = idx & 255;
  float score = 0.f, nz = 0.f;
  for (int p = 0; p < P; ++p) {
    float se = 0.f, st = 0.f, dot = 0.f;
    for (int d = 0; d < D; ++d) {
      float ev = enroll[((size_t)a * D + d) * P + p];
      float tv = test[((size_t)b * D + d) * P + p];
      se = fmaf(ev, ev, se);
      st = fmaf(tv, tv, st);
      dot = fmaf(ev, tv, dot);
    }
    float s = dot * (1.0f / fmaxf(sqrtf(se), 1e-12f)) * (1.0f / fmaxf(sqrtf(st), 1e-12f));
    float g = 0.f;
#pragma unroll
    for (int c = 0; c < C; ++c) g = fmaf(tanh_fast(fmaf(s, w1[c], b1[c])), w2[c], g);
    float f = tanh_fast(g * s);
    score = fmaf(f, pwm[p], score);
    if (s != 0.0f) nz += pwm[p];
  }
  out[idx] = score / (nz + 1e-6f);
}

}  // namespace

extern "C" void kernel_launch(void* const* d_in, const int* in_sizes, int n_in,
                              void* d_out, int out_size, void* d_ws, size_t ws_size,
                              hipStream_t stream) {
  const float* enroll = (const float*)d_in[0];
  const float* test = (const float*)d_in[1];
  const float* pho_w = (const float*)d_in[2];
  const float* fc1w = (const float*)d_in[3];
  const float* fc1b = (const float*)d_in[4];
  const float* fc2w = (const float*)d_in[5];
  float* out = (float*)d_out;

  const size_t sz_pair = (size_t)P * K * 256 * sizeof(unsigned);  // 10.49 MB each
  const size_t need = 2 * sz_pair + (size_t)2 * NOUT * sizeof(float) +
                      64 * sizeof(unsigned) + (size_t)(LN + 8) * sizeof(float) +
                      (size_t)(P + 1) * sizeof(float);
  if (ws_size >= need) {
    unsigned* Ep = (unsigned*)d_ws;
    unsigned* Tp = Ep + sz_pair / 4;
    float* accS = (float*)(Tp + sz_pair / 4);
    float* corr = accS + NOUT;
    unsigned* cnt = (unsigned*)(corr + NOUT);
    float* tab = (float*)(cnt + 64);
    float* pwv = tab + (LN + 4);

    kprep<<<2 * K + ZB + LB + 1, 256, 0, stream>>>(enroll, test, fc1w, fc1b, fc2w, pho_w,
                                                   Ep, Tp, accS, tab, pwv, cnt);
    kgemm<<<NGP * 32, 256, 0, stream>>>(Ep, Tp, tab, pwv, accS, corr, cnt, out);
  } else {
    kmono<<<(K * K) / 256, 256, 0, stream>>>(enroll, test, pho_w, fc1w, fc1b, fc2w, out);
  }
}

// Round 8
// 44.310 us; speedup vs baseline: 1.7991x; 1.7991x over previous
//
#include <hip/hip_runtime.h>
#include <math.h>

namespace {

constexpr int K = 256, D = 256, P = 40, C = 32;
constexpr int LN = 2048;     // LUT intervals over s in [-1,1]
constexpr int NOUT = K * K;  // 65536
constexpr int ZB = 128;                   // zero-blocks: 128*256*16B = 512 KB (accS+corr)
constexpr int LB = (LN + 1 + 255) / 256;  // LUT blocks

typedef __attribute__((ext_vector_type(8))) short bf16x8;
typedef __attribute__((ext_vector_type(4))) float f32x4;

__device__ __forceinline__ float tanh_fast(float x) {
  float e = __expf(2.0f * x);
  return 1.0f - __fdividef(2.0f, e + 1.0f);
}

// round-to-nearest bf16 split: (hi16) | (lo16 << 16); hi+lo ~ v to ~2^-18 rel
__device__ __forceinline__ unsigned bf16pair(float v) {
  unsigned u = __float_as_uint(v);
  unsigned hi = (u + 0x7fffu + ((u >> 16) & 1u)) >> 16;
  float lo = v - __uint_as_float(hi << 16);
  unsigned ul = __float_as_uint(lo);
  unsigned lo16 = (ul + 0x7fffu + ((ul >> 16) & 1u)) >> 16;
  return hi | (lo16 << 16);
}

__device__ __forceinline__ void gload16(const void* g, void* l) {
  __builtin_amdgcn_global_load_lds((const __attribute__((address_space(1))) void*)g,
                                   (__attribute__((address_space(3))) void*)l, 16, 0, 0);
}

// ---- prep (+ merged init): blocks [0,2K): L2-norm+transpose+bf16-split;
//      then ZB zero-blocks (accS/corr); then LUT blocks; then pw block ----
__global__ __launch_bounds__(256) void kprep(const float* __restrict__ e,
                                             const float* __restrict__ ts,
                                             const float* __restrict__ fc1w,
                                             const float* __restrict__ fc1b,
                                             const float* __restrict__ fc2w,
                                             const float* __restrict__ pho_w,
                                             unsigned* __restrict__ Ep,
                                             unsigned* __restrict__ Tp,
                                             float* __restrict__ accz,
                                             float* __restrict__ tab,
                                             float* __restrict__ pwv) {
  const int bid = blockIdx.x;
  const int t = threadIdx.x;
  if (bid >= 2 * K) {
    int ib = bid - 2 * K;
    if (ib < ZB) {
      ((float4*)accz)[(size_t)ib * 256 + t] = make_float4(0.f, 0.f, 0.f, 0.f);
      return;
    }
    ib -= ZB;
    if (ib < LB) {
      int i = ib * 256 + t;
      if (i <= LN) {
        float s = -1.0f + (float)i * (2.0f / LN);
        float g = 0.f;
#pragma unroll
        for (int c = 0; c < C; ++c) g = fmaf(tanh_fast(fmaf(s, fc1w[c], fc1b[c])), fc2w[c], g);
        tab[i] = tanh_fast(g * s);
      }
      return;
    }
    // pw block: pwv[0..P) normalized weights, pwv[P] = sum
    float wmin = pho_w[0], wmax = pho_w[0];
    for (int i = 1; i < P; ++i) {
      float v = pho_w[i];
      wmin = fminf(wmin, v);
      wmax = fmaxf(wmax, v);
    }
    float inv = 1.0f / (1e-6f + wmax - wmin);
    if (t < P) pwv[t] = (pho_w[t] - wmin) * inv;
    if (t == 64) {
      float sum = 0.f;
      for (int i = 0; i < P; ++i) sum += (pho_w[i] - wmin) * inv;
      pwv[P] = sum;
    }
    return;
  }
  // ---- prep path ----
  __shared__ float tile[D * 41];  // padded stride 41
  __shared__ float red[240];
  __shared__ float inv[P];
  const float* x = (bid < K) ? e : ts;
  unsigned* xt = (bid < K) ? Ep : Tp;
  const int a = bid & (K - 1);
  const float4* src4 = (const float4*)(x + (size_t)a * D * P);
#pragma unroll
  for (int i4 = t; i4 < (D * P) / 4; i4 += 256) {
    float4 v = src4[i4];
    int d = i4 / 10;
    int p0 = (i4 - d * 10) * 4;
    float* dst = &tile[d * 41 + p0];
    dst[0] = v.x;
    dst[1] = v.y;
    dst[2] = v.z;
    dst[3] = v.w;
  }
  __syncthreads();
  if (t < 240) {  // 6 threads per column
    int p = t / 6, j = t - (t / 6) * 6;
    float ss = 0.f;
    for (int d = j; d < D; d += 6) {
      float v = tile[d * 41 + p];
      ss = fmaf(v, v, ss);
    }
    red[t] = ss;
  }
  __syncthreads();
  if (t < P) {
    float ss = red[t * 6] + red[t * 6 + 1] + red[t * 6 + 2] + red[t * 6 + 3] +
               red[t * 6 + 4] + red[t * 6 + 5];
    inv[t] = 1.0f / fmaxf(sqrtf(ss), 1e-12f);
  }
  __syncthreads();
  for (int i = t; i < (D * P) / 2; i += 256) {
    int p = i >> 7, d = (i & 127) * 2;
    float iv = inv[p];
    unsigned u0 = bf16pair(tile[d * 41 + p] * iv);
    unsigned u1 = bf16pair(tile[(d + 1) * 41 + p] * iv);
    *(uint2*)&xt[((size_t)p * K + a) * 256 + d] = make_uint2(u0, u1);
  }
}

// ---- per-p MFMA GEMM (split-K=512 bf16), 32x32 tile, SINGLE-SHOT staging:
//      whole A/B panels (64 KB) -> one barrier -> 16 straight MFMAs/wave ----
__global__ __launch_bounds__(256) void kgemm(const unsigned* __restrict__ Ep,
                                             const unsigned* __restrict__ Tp,
                                             const float* __restrict__ tab,
                                             const float* __restrict__ pwv,
                                             float* __restrict__ accS,
                                             float* __restrict__ corr) {
  __shared__ __align__(16) char As[32 * 1024];  // 32 rows x 1 KB (K=512 bf16)
  __shared__ __align__(16) char Bs[32 * 1024];
  const int p = blockIdx.z;
  const int b0 = blockIdx.x * 32, a0 = blockIdx.y * 32;
  const int t = threadIdx.x, lane = t & 63, w = t >> 6;
  const char* ce = (const char*)Ep + (size_t)p * (K * 1024);
  const char* ct = (const char*)Tp + (size_t)p * (K * 1024);

  // stage: wave w fills rows {w, 4+w, ..., 28+w}; linear LDS dest (base+lane*16),
  // pre-swizzled global source; read side applies the same XOR (rule: both-sides)
  const int lsw = lane * 16;
#pragma unroll
  for (int i = 0; i < 8; ++i) {
    const int r = i * 4 + w;
    const int so = lsw ^ ((r & 7) << 4);
    gload16(ce + (size_t)(a0 + r) * 1024 + so, As + r * 1024);
    gload16(ct + (size_t)(b0 + r) * 1024 + so, Bs + r * 1024);
  }
  __syncthreads();  // single drain: all 64 KB resident

  // compute: wave w owns quadrant (qr, qc); 16 MFMAs over K=512
  const int qr = (w >> 1) * 16, qc = (w & 1) * 16;
  const int l15 = lane & 15, hi16 = (lane >> 4) * 16;
  const int rsw = (l15 & 7) << 4;
  const char* Ar = As + (size_t)(qr + l15) * 1024;
  const char* Br = Bs + (size_t)(qc + l15) * 1024;
  f32x4 acc = {0.f, 0.f, 0.f, 0.f};
#pragma unroll
  for (int ks = 0; ks < 16; ++ks) {
    const int off = (ks * 64 + hi16) ^ rsw;
    bf16x8 af = *(const bf16x8*)(Ar + off);
    bf16x8 bf = *(const bf16x8*)(Br + off);
    acc = __builtin_amdgcn_mfma_f32_16x16x32_bf16(af, bf, acc, 0, 0, 0);
  }

  // epilogue: LUT via L2 (8 KB table, hot everywhere), weighted atomics
  const float pwp = pwv[p];
  const int ar = a0 + qr + (lane >> 4) * 4;
  const int bc = b0 + qc + l15;
#pragma unroll
  for (int j = 0; j < 4; ++j) {
    float s = acc[j];
    float u = fminf(fmaxf((s + 1.0f) * (LN / 2), 0.0f), (float)LN);
    int i = min((int)u, LN - 1);
    float lt0 = tab[i], lt1 = tab[i + 1];
    float F = fmaf(u - (float)i, lt1 - lt0, lt0);
    atomicAdd(&accS[(ar + j) * K + bc], F * pwp);
    if (s == 0.0f) atomicAdd(&corr[(ar + j) * K + bc], pwp);  // never taken on real data
  }
}

// ---- finalize ----
__global__ __launch_bounds__(256) void kdiv(const float* __restrict__ accS,
                                            const float* __restrict__ corr,
                                            const float* __restrict__ pwv,
                                            float* __restrict__ out) {
  int gi = blockIdx.x * 256 + threadIdx.x;
  out[gi] = accS[gi] / (pwv[P] - corr[gi] + 1e-6f);
}

// ---- emergency fallback (no workspace needed) ----
__global__ __launch_bounds__(256) void kmono(const float* __restrict__ enroll,
                                             const float* __restrict__ test,
                                             const float* __restrict__ pho_w,
                                             const float* __restrict__ fc1w,
                                             const float* __restrict__ fc1b,
                                             const float* __restrict__ fc2w,
                                             float* __restrict__ out) {
  __shared__ float w1[C], b1[C], w2[C], pwm[P];
  const int t = threadIdx.x;
  if (t < C) {
    w1[t] = fc1w[t];
    b1[t] = fc1b[t];
    w2[t] = fc2w[t];
  }
  if (t < P) {
    float wmin = pho_w[0], wmax = pho_w[0];
    for (int i = 1; i < P; ++i) {
      float v = pho_w[i];
      wmin = fminf(wmin, v);
      wmax = fmaxf(wmax, v);
    }
    pwm[t] = (pho_w[t] - wmin) / (1e-6f + wmax - wmin);
  }
  __syncthreads();
  const int idx = blockIdx.x * 256 + t;
  const int a = idx >> 8, b = idx & 255;
  float score = 0.f, nz = 0.f;
  for (int p = 0; p < P; ++p) {
    float se = 0.f, st = 0.f, dot = 0.f;
    for (int d = 0; d < D; ++d) {
      float ev = enroll[((size_t)a * D + d) * P + p];
      float tv = test[((size_t)b * D + d) * P + p];
      se = fmaf(ev, ev, se);
      st = fmaf(tv, tv, st);
      dot = fmaf(ev, tv, dot);
    }
    float s = dot * (1.0f / fmaxf(sqrtf(se), 1e-12f)) * (1.0f / fmaxf(sqrtf(st), 1e-12f));
    float g = 0.f;
#pragma unroll
    for (int c = 0; c < C; ++c) g = fmaf(tanh_fast(fmaf(s, w1[c], b1[c])), w2[c], g);
    float f = tanh_fast(g * s);
    score = fmaf(f, pwm[p], score);
    if (s != 0.0f) nz += pwm[p];
  }
  out[idx] = score / (nz + 1e-6f);
}

}  // namespace

extern "C" void kernel_launch(void* const* d_in, const int* in_sizes, int n_in,
                              void* d_out, int out_size, void* d_ws, size_t ws_size,
                              hipStream_t stream) {
  const float* enroll = (const float*)d_in[0];
  const float* test = (const float*)d_in[1];
  const float* pho_w = (const float*)d_in[2];
  const float* fc1w = (const float*)d_in[3];
  const float* fc1b = (const float*)d_in[4];
  const float* fc2w = (const float*)d_in[5];
  float* out = (float*)d_out;

  const size_t sz_pair = (size_t)P * K * 256 * sizeof(unsigned);  // 10.49 MB each
  const size_t need = 2 * sz_pair + (size_t)2 * NOUT * sizeof(float) +
                      (size_t)(LN + 8) * sizeof(float) + (size_t)(P + 1) * sizeof(float);
  if (ws_size >= need) {
    unsigned* Ep = (unsigned*)d_ws;
    unsigned* Tp = Ep + sz_pair / 4;
    float* accS = (float*)(Tp + sz_pair / 4);
    float* corr = accS + NOUT;
    float* tab = corr + NOUT;
    float* pwv = tab + (LN + 4);

    kprep<<<2 * K + ZB + LB + 1, 256, 0, stream>>>(enroll, test, fc1w, fc1b, fc2w, pho_w,
                                                   Ep, Tp, accS, tab, pwv);
    kgemm<<<dim3(K / 32, K / 32, P), 256, 0, stream>>>(Ep, Tp, tab, pwv, accS, corr);
    kdiv<<<NOUT / 256, 256, 0, stream>>>(accS, corr, pwv, out);
  } else {
    kmono<<<(K * K) / 256, 256, 0, stream>>>(enroll, test, pho_w, fc1w, fc1b, fc2w, out);
  }
}

// Round 9
// 42.725 us; speedup vs baseline: 1.8659x; 1.0371x over previous
//
#include <hip/hip_runtime.h>
#include <math.h>

namespace {

constexpr int K = 256, D = 256, P = 40, C = 32;
constexpr int LN = 2048;     // LUT intervals over s in [-1,1]
constexpr int NOUT = K * K;  // 65536
constexpr int ZB = 128;                   // zero-blocks: 128*256*16B = 512 KB (accS+corr)
constexpr int LB = (LN + 1 + 255) / 256;  // LUT blocks

typedef __attribute__((ext_vector_type(8))) short bf16x8;
typedef __attribute__((ext_vector_type(4))) float f32x4;

__device__ __forceinline__ float tanh_fast(float x) {
  float e = __expf(2.0f * x);
  return 1.0f - __fdividef(2.0f, e + 1.0f);
}

// round-to-nearest bf16 split: (hi16) | (lo16 << 16); hi+lo ~ v to ~2^-18 rel
__device__ __forceinline__ unsigned bf16pair(float v) {
  unsigned u = __float_as_uint(v);
  unsigned hi = (u + 0x7fffu + ((u >> 16) & 1u)) >> 16;
  float lo = v - __uint_as_float(hi << 16);
  unsigned ul = __float_as_uint(lo);
  unsigned lo16 = (ul + 0x7fffu + ((ul >> 16) & 1u)) >> 16;
  return hi | (lo16 << 16);
}

__device__ __forceinline__ void gload16(const void* g, void* l) {
  __builtin_amdgcn_global_load_lds((const __attribute__((address_space(1))) void*)g,
                                   (__attribute__((address_space(3))) void*)l, 16, 0, 0);
}

// ---- prep (+ merged init): blocks [0,2K): L2-norm+transpose+bf16-split;
//      then ZB zero-blocks (accS/corr); then LUT blocks; then pw block ----
__global__ __launch_bounds__(256) void kprep(const float* __restrict__ e,
                                             const float* __restrict__ ts,
                                             const float* __restrict__ fc1w,
                                             const float* __restrict__ fc1b,
                                             const float* __restrict__ fc2w,
                                             const float* __restrict__ pho_w,
                                             unsigned* __restrict__ Ep,
                                             unsigned* __restrict__ Tp,
                                             float* __restrict__ accz,
                                             float* __restrict__ tab,
                                             float* __restrict__ pwv) {
  const int bid = blockIdx.x;
  const int t = threadIdx.x;
  if (bid >= 2 * K) {
    int ib = bid - 2 * K;
    if (ib < ZB) {
      ((float4*)accz)[(size_t)ib * 256 + t] = make_float4(0.f, 0.f, 0.f, 0.f);
      return;
    }
    ib -= ZB;
    if (ib < LB) {
      int i = ib * 256 + t;
      if (i <= LN) {
        float s = -1.0f + (float)i * (2.0f / LN);
        float g = 0.f;
#pragma unroll
        for (int c = 0; c < C; ++c) g = fmaf(tanh_fast(fmaf(s, fc1w[c], fc1b[c])), fc2w[c], g);
        tab[i] = tanh_fast(g * s);
      }
      return;
    }
    // pw block: pwv[0..P) normalized weights, pwv[P] = sum
    float wmin = pho_w[0], wmax = pho_w[0];
    for (int i = 1; i < P; ++i) {
      float v = pho_w[i];
      wmin = fminf(wmin, v);
      wmax = fmaxf(wmax, v);
    }
    float inv = 1.0f / (1e-6f + wmax - wmin);
    if (t < P) pwv[t] = (pho_w[t] - wmin) * inv;
    if (t == 64) {
      float sum = 0.f;
      for (int i = 0; i < P; ++i) sum += (pho_w[i] - wmin) * inv;
      pwv[P] = sum;
    }
    return;
  }
  // ---- prep path ----
  __shared__ float tile[D * 41];  // padded stride 41
  __shared__ float red[240];
  __shared__ float inv[P];
  const float* x = (bid < K) ? e : ts;
  unsigned* xt = (bid < K) ? Ep : Tp;
  const int a = bid & (K - 1);
  const float4* src4 = (const float4*)(x + (size_t)a * D * P);
#pragma unroll
  for (int i4 = t; i4 < (D * P) / 4; i4 += 256) {
    float4 v = src4[i4];
    int d = i4 / 10;
    int p0 = (i4 - d * 10) * 4;
    float* dst = &tile[d * 41 + p0];
    dst[0] = v.x;
    dst[1] = v.y;
    dst[2] = v.z;
    dst[3] = v.w;
  }
  __syncthreads();
  if (t < 240) {  // 6 threads per column
    int p = t / 6, j = t - (t / 6) * 6;
    float ss = 0.f;
    for (int d = j; d < D; d += 6) {
      float v = tile[d * 41 + p];
      ss = fmaf(v, v, ss);
    }
    red[t] = ss;
  }
  __syncthreads();
  if (t < P) {
    float ss = red[t * 6] + red[t * 6 + 1] + red[t * 6 + 2] + red[t * 6 + 3] +
               red[t * 6 + 4] + red[t * 6 + 5];
    inv[t] = 1.0f / fmaxf(sqrtf(ss), 1e-12f);
  }
  __syncthreads();
  for (int i = t; i < (D * P) / 2; i += 256) {
    int p = i >> 7, d = (i & 127) * 2;
    float iv = inv[p];
    unsigned u0 = bf16pair(tile[d * 41 + p] * iv);
    unsigned u1 = bf16pair(tile[(d + 1) * 41 + p] * iv);
    *(uint2*)&xt[((size_t)p * K + a) * 256 + d] = make_uint2(u0, u1);
  }
}

// ---- per-p MFMA GEMM (split-K=512 bf16), 32x32 tile, single-shot staging,
//      XCD-grouped decode: each XCD owns 5 p-slices -> panels stay L2-resident ----
__global__ __launch_bounds__(256) void kgemm(const unsigned* __restrict__ Ep,
                                             const unsigned* __restrict__ Tp,
                                             const float* __restrict__ tab,
                                             const float* __restrict__ pwv,
                                             float* __restrict__ accS,
                                             float* __restrict__ corr) {
  __shared__ __align__(16) char As[32 * 1024];  // 32 rows x 1 KB (K=512 bf16)
  __shared__ __align__(16) char Bs[32 * 1024];
  // XCD-grouped decode (assumes consecutive blockIdx round-robin across 8 XCDs):
  // xcd = id&7 gets p in {xcd, xcd+8, ..., xcd+32}; 64 tiles per (xcd, p).
  const int id = blockIdx.x;
  const int xcd = id & 7, slot = id >> 3;
  const int p = xcd + 8 * (slot >> 6);
  const int tile = slot & 63;
  const int a0 = (tile >> 3) * 32, b0 = (tile & 7) * 32;
  const int t = threadIdx.x, lane = t & 63, w = t >> 6;
  const char* ce = (const char*)Ep + (size_t)p * (K * 1024);
  const char* ct = (const char*)Tp + (size_t)p * (K * 1024);

  // stage: wave w fills rows {w, 4+w, ..., 28+w}; linear LDS dest (base+lane*16),
  // pre-swizzled global source; read side applies the same XOR (both-sides rule)
  const int lsw = lane * 16;
#pragma unroll
  for (int i = 0; i < 8; ++i) {
    const int r = i * 4 + w;
    const int so = lsw ^ ((r & 7) << 4);
    gload16(ce + (size_t)(a0 + r) * 1024 + so, As + r * 1024);
    gload16(ct + (size_t)(b0 + r) * 1024 + so, Bs + r * 1024);
  }
  __syncthreads();  // single drain: all 64 KB resident

  // compute: wave w owns quadrant (qr, qc); 16 MFMAs over K=512
  const int qr = (w >> 1) * 16, qc = (w & 1) * 16;
  const int l15 = lane & 15, hi16 = (lane >> 4) * 16;
  const int rsw = (l15 & 7) << 4;
  const char* Ar = As + (size_t)(qr + l15) * 1024;
  const char* Br = Bs + (size_t)(qc + l15) * 1024;
  f32x4 acc = {0.f, 0.f, 0.f, 0.f};
#pragma unroll
  for (int ks = 0; ks < 16; ++ks) {
    const int off = (ks * 64 + hi16) ^ rsw;
    bf16x8 af = *(const bf16x8*)(Ar + off);
    bf16x8 bf = *(const bf16x8*)(Br + off);
    acc = __builtin_amdgcn_mfma_f32_16x16x32_bf16(af, bf, acc, 0, 0, 0);
  }

  // epilogue: LUT via L2 (8 KB table, hot per-XCD), weighted atomics
  const float pwp = pwv[p];
  const int ar = a0 + qr + (lane >> 4) * 4;
  const int bc = b0 + qc + l15;
#pragma unroll
  for (int j = 0; j < 4; ++j) {
    float s = acc[j];
    float u = fminf(fmaxf((s + 1.0f) * (LN / 2), 0.0f), (float)LN);
    int i = min((int)u, LN - 1);
    float lt0 = tab[i], lt1 = tab[i + 1];
    float F = fmaf(u - (float)i, lt1 - lt0, lt0);
    atomicAdd(&accS[(ar + j) * K + bc], F * pwp);
    if (s == 0.0f) atomicAdd(&corr[(ar + j) * K + bc], pwp);  // never taken on real data
  }
}

// ---- finalize ----
__global__ __launch_bounds__(256) void kdiv(const float* __restrict__ accS,
                                            const float* __restrict__ corr,
                                            const float* __restrict__ pwv,
                                            float* __restrict__ out) {
  int gi = blockIdx.x * 256 + threadIdx.x;
  out[gi] = accS[gi] / (pwv[P] - corr[gi] + 1e-6f);
}

// ---- emergency fallback (no workspace needed) ----
__global__ __launch_bounds__(256) void kmono(const float* __restrict__ enroll,
                                             const float* __restrict__ test,
                                             const float* __restrict__ pho_w,
                                             const float* __restrict__ fc1w,
                                             const float* __restrict__ fc1b,
                                             const float* __restrict__ fc2w,
                                             float* __restrict__ out) {
  __shared__ float w1[C], b1[C], w2[C], pwm[P];
  const int t = threadIdx.x;
  if (t < C) {
    w1[t] = fc1w[t];
    b1[t] = fc1b[t];
    w2[t] = fc2w[t];
  }
  if (t < P) {
    float wmin = pho_w[0], wmax = pho_w[0];
    for (int i = 1; i < P; ++i) {
      float v = pho_w[i];
      wmin = fminf(wmin, v);
      wmax = fmaxf(wmax, v);
    }
    pwm[t] = (pho_w[t] - wmin) / (1e-6f + wmax - wmin);
  }
  __syncthreads();
  const int idx = blockIdx.x * 256 + t;
  const int a = idx >> 8, b = idx & 255;
  float score = 0.f, nz = 0.f;
  for (int p = 0; p < P; ++p) {
    float se = 0.f, st = 0.f, dot = 0.f;
    for (int d = 0; d < D; ++d) {
      float ev = enroll[((size_t)a * D + d) * P + p];
      float tv = test[((size_t)b * D + d) * P + p];
      se = fmaf(ev, ev, se);
      st = fmaf(tv, tv, st);
      dot = fmaf(ev, tv, dot);
    }
    float s = dot * (1.0f / fmaxf(sqrtf(se), 1e-12f)) * (1.0f / fmaxf(sqrtf(st), 1e-12f));
    float g = 0.f;
#pragma unroll
    for (int c = 0; c < C; ++c) g = fmaf(tanh_fast(fmaf(s, w1[c], b1[c])), w2[c], g);
    float f = tanh_fast(g * s);
    score = fmaf(f, pwm[p], score);
    if (s != 0.0f) nz += pwm[p];
  }
  out[idx] = score / (nz + 1e-6f);
}

}  // namespace

extern "C" void kernel_launch(void* const* d_in, const int* in_sizes, int n_in,
                              void* d_out, int out_size, void* d_ws, size_t ws_size,
                              hipStream_t stream) {
  const float* enroll = (const float*)d_in[0];
  const float* test = (const float*)d_in[1];
  const float* pho_w = (const float*)d_in[2];
  const float* fc1w = (const float*)d_in[3];
  const float* fc1b = (const float*)d_in[4];
  const float* fc2w = (const float*)d_in[5];
  float* out = (float*)d_out;

  const size_t sz_pair = (size_t)P * K * 256 * sizeof(unsigned);  // 10.49 MB each
  const size_t need = 2 * sz_pair + (size_t)2 * NOUT * sizeof(float) +
                      (size_t)(LN + 8) * sizeof(float) + (size_t)(P + 1) * sizeof(float);
  if (ws_size >= need) {
    unsigned* Ep = (unsigned*)d_ws;
    unsigned* Tp = Ep + sz_pair / 4;
    float* accS = (float*)(Tp + sz_pair / 4);
    float* corr = accS + NOUT;
    float* tab = corr + NOUT;
    float* pwv = tab + (LN + 4);

    kprep<<<2 * K + ZB + LB + 1, 256, 0, stream>>>(enroll, test, fc1w, fc1b, fc2w, pho_w,
                                                   Ep, Tp, accS, tab, pwv);
    kgemm<<<8 * 5 * 64, 256, 0, stream>>>(Ep, Tp, tab, pwv, accS, corr);
    kdiv<<<NOUT / 256, 256, 0, stream>>>(accS, corr, pwv, out);
  } else {
    kmono<<<(K * K) / 256, 256, 0, stream>>>(enroll, test, pho_w, fc1w, fc1b, fc2w, out);
  }
}